// Round 20
// baseline (263.430 us; speedup 1.0000x reference)
//
#include <hip/hip_runtime.h>
#include <hip/hip_bf16.h>

typedef __attribute__((ext_vector_type(8))) _Float16 half8_t;
typedef __attribute__((ext_vector_type(4))) _Float16 half4_t;
typedef __attribute__((ext_vector_type(4))) float float4_t;

#define D_DIM 768
#define S_DIM 4096
#define B_DIM 4
#define M_DIM (B_DIM * S_DIM)  // 16384
#define SD ((size_t)S_DIM * D_DIM)

#define GLOAD_LDS16(g, s)                                      \
  __builtin_amdgcn_global_load_lds(                            \
      (const __attribute__((address_space(1))) void*)(g),      \
      (__attribute__((address_space(3))) void*)(s), 16, 0, 0)

__device__ __forceinline__ float4_t mfma16(half8_t a, half8_t b, float4_t c) {
  return __builtin_amdgcn_mfma_f32_16x16x32_f16(a, b, c, 0, 0, 0);
}

// ---------------- fused pre-pass: x -> fp16 AND W -> WT (one dispatch) ----------
// blocks [0, 12288): cvt_x (4 floats/thread). blocks [12288, 12720): W transpose.
__global__ __launch_bounds__(256) void prep_kernel(const float* __restrict__ x,
                                                   const float* __restrict__ W0,
                                                   const float* __restrict__ W1,
                                                   const float* __restrict__ W2,
                                                   _Float16* __restrict__ xh,
                                                   _Float16* __restrict__ WT) {
  __shared__ _Float16 tile[64][68];
  const int bid = blockIdx.x;
  if (bid < 12288) {
    int i = (bid * 256 + threadIdx.x) * 4;
    float4 v = *(const float4*)(x + i);
    half4_t o;
    o.x = (_Float16)v.x; o.y = (_Float16)v.y; o.z = (_Float16)v.z; o.w = (_Float16)v.w;
    *(half4_t*)(xh + i) = o;
  } else {
    int t = bid - 12288;
    int z = t / 144;
    int r = t % 144;
    int kx = r / 12, ny = r % 12;
    const float* W = (z == 0) ? W0 : (z == 1) ? W1 : W2;
    _Float16* o = WT + (size_t)z * D_DIM * D_DIM;
    int k0 = kx * 64, n0 = ny * 64;
#pragma unroll
    for (int i = 0; i < 16; ++i) {
      int idx = threadIdx.x + i * 256;
      int rr = idx >> 6, cc = idx & 63;
      tile[rr][cc] = (_Float16)W[(size_t)(k0 + rr) * D_DIM + n0 + cc];
    }
    __syncthreads();
#pragma unroll
    for (int i = 0; i < 16; ++i) {
      int idx = threadIdx.x + i * 256;
      int rr = idx >> 6, cc = idx & 63;
      o[(size_t)(n0 + rr) * D_DIM + k0 + cc] = tile[cc][rr];
    }
  }
}

// ============ m97-style 4-wave GEMM core: BM=BN=128, BK=64, SINGLE 32 KB buffer ====
// 256 thr = 4 waves (wr=w>>1, wc=w&1), wave tile 64x64 (4x4 frags, 64 AGPR acc).
// Per K-step: STG (8 global_load_lds) -> __syncthreads -> 16 ds_read_b128 +
// 32 MFMA -> __syncthreads. 3 blocks/CU co-resident; cross-block overlap hides
// the drain (m114/m97 structure; best measured operating point, rounds 13-19).
// Granule swizzle u' = u ^ (row&7) (verified conflict-free, rounds 12-17).
template <bool SWAP>
__device__ __forceinline__ void core128(const _Float16* __restrict__ Ag,
                                        const _Float16* __restrict__ Bg,
                                        int lda, int ldb, int nt,
                                        char* lds, float4_t (&acc)[4][4]) {
  const int tid = threadIdx.x;
  const int w = tid >> 6, l = tid & 63;
  const int wr = w >> 1, wc = w & 1;
  const int l15 = l & 15, l4 = l >> 4;

  int sA[4], sB[4], sDst[4];
#pragma unroll
  for (int i = 0; i < 4; ++i) {
    int L = i * 256 + tid;
    int row = L >> 3, u = L & 7;
    int usw = u ^ (row & 7);
    sA[i] = row * lda + usw * 8;
    sB[i] = row * ldb + usw * 8;
    sDst[i] = (i * 256 + (tid & ~63)) * 16;
  }

  int aOff[2][4], bOff[2][4];
#pragma unroll
  for (int ks = 0; ks < 2; ++ks) {
#pragma unroll
    for (int i = 0; i < 4; ++i) {
      int ar = wr * 64 + i * 16 + l15;
      aOff[ks][i] = ar * 128 + (((ks * 4 + l4) ^ (ar & 7)) * 16);
      int br = wc * 64 + i * 16 + l15;
      bOff[ks][i] = 16384 + br * 128 + (((ks * 4 + l4) ^ (br & 7)) * 16);
    }
  }

#pragma unroll 1
  for (int kt = 0; kt < nt; ++kt) {
#pragma unroll
    for (int i = 0; i < 4; ++i)
      GLOAD_LDS16(Ag + (size_t)kt * 64 + sA[i], lds + sDst[i]);
#pragma unroll
    for (int i = 0; i < 4; ++i)
      GLOAD_LDS16(Bg + (size_t)kt * 64 + sB[i], lds + 16384 + sDst[i]);
    __syncthreads();  // drains vmcnt -> tile in LDS for all waves
#pragma unroll
    for (int ks = 0; ks < 2; ++ks) {
      half8_t af[4], bf[4];
#pragma unroll
      for (int ni = 0; ni < 4; ++ni) bf[ni] = *(const half8_t*)(lds + bOff[ks][ni]);
#pragma unroll
      for (int mi = 0; mi < 4; ++mi) af[mi] = *(const half8_t*)(lds + aOff[ks][mi]);
      __builtin_amdgcn_s_setprio(1);
#pragma unroll
      for (int mi = 0; mi < 4; ++mi)
#pragma unroll
        for (int ni = 0; ni < 4; ++ni) {
          if (SWAP)
            acc[mi][ni] = mfma16(bf[ni], af[mi], acc[mi][ni]);
          else
            acc[mi][ni] = mfma16(af[mi], bf[ni], acc[mi][ni]);
        }
      __builtin_amdgcn_s_setprio(0);
    }
    __syncthreads();  // all reads done before next stage overwrites
  }
}

// ---------------- proj: q,k normal; v written directly transposed ----------------
// grid 2304 = 8 x 288 (XCD-bijective). wid = rbg*18 + z*6 + cb. (round-14/17 best)
__global__ __launch_bounds__(256) void proj8_kernel(const _Float16* __restrict__ xh,
                                                    const _Float16* __restrict__ WT,
                                                    _Float16* __restrict__ qkv,
                                                    _Float16* __restrict__ vt) {
  __shared__ __align__(16) char lds[32768];
  const int bid = blockIdx.x;
  const int wid = (bid & 7) * 288 + (bid >> 3);
  const int rbg = wid / 18;
  const int rem = wid % 18;
  const int z = rem / 6;
  const int cb = rem % 6;

  const _Float16* Ag = xh + (size_t)rbg * 128 * D_DIM;
  const _Float16* Bg = WT + (size_t)z * D_DIM * D_DIM + (size_t)cb * 128 * D_DIM;
  float4_t acc[4][4];
#pragma unroll
  for (int a = 0; a < 4; ++a)
#pragma unroll
    for (int b = 0; b < 4; ++b) acc[a][b] = (float4_t){0.f, 0.f, 0.f, 0.f};

  const int tid = threadIdx.x;
  const int w = tid >> 6, l = tid & 63;
  const int wr = w >> 1, wc = w & 1;
  const int l15 = l & 15, l4 = l >> 4;

  if (z < 2) {
    core128<false>(Ag, Bg, D_DIM, D_DIM, 12, lds, acc);
    _Float16* C = qkv + (size_t)z * M_DIM * D_DIM;
#pragma unroll
    for (int mi = 0; mi < 4; ++mi)
#pragma unroll
      for (int ni = 0; ni < 4; ++ni) {
        int col = cb * 128 + wc * 64 + ni * 16 + l15;
#pragma unroll
        for (int j = 0; j < 4; ++j) {
          int row = rbg * 128 + wr * 64 + mi * 16 + l4 * 4 + j;
          C[(size_t)row * D_DIM + col] = (_Float16)acc[mi][ni][j];
        }
      }
  } else {
    core128<true>(Ag, Bg, D_DIM, D_DIM, 12, lds, acc);
    // acc holds transposed tile: out-row = W-row (d), out-col = x-row (s)
#pragma unroll
    for (int mi = 0; mi < 4; ++mi) {
      int scol = rbg * 128 + wr * 64 + mi * 16 + l15;
      int bb = scol >> 12;
      int sl = scol & 4095;
      _Float16* vtb = vt + (size_t)bb * SD;
#pragma unroll
      for (int ni = 0; ni < 4; ++ni) {
#pragma unroll
        for (int j = 0; j < 4; ++j) {
          int drow = cb * 128 + wc * 64 + ni * 16 + l4 * 4 + j;
          vtb[(size_t)drow * S_DIM + sl] = (_Float16)acc[mi][ni][j];
        }
      }
    }
  }
}

// ---------------- gemm1: P = exp(scale*QK^T - 4) causal ----------------
// grid 2112 = 8 x 264. Per z: 528 lower-triangle 128^2 blocks, 4x4-supertiled.
__global__ __launch_bounds__(256) void gemm1_8_kernel(const _Float16* __restrict__ Q,
                                                      const _Float16* __restrict__ K,
                                                      _Float16* __restrict__ P,
                                                      float* __restrict__ rp) {
  __shared__ __align__(16) char lds[32768];
  const float SCALE = 0.036084391824351615f;  // 1/sqrt(768)
  const int bid = blockIdx.x;
  const int wid = (bid & 7) * 264 + (bid >> 3);
  const int z = wid / 528;
  const int t = wid % 528;
  int g = 0;
  while (g < 7 && (8 * (g + 1) * g + 10 * (g + 1)) <= t) ++g;
  int r = t - (8 * g * (g - 1) + 10 * g);
  int rbg, cb;
  if (r < 16 * g) {
    int cbg = r >> 4, wi = r & 15;
    rbg = 4 * g + (wi >> 2);
    cb = 4 * cbg + (wi & 3);
  } else {
    int r2 = r - 16 * g;
    const int ri[10] = {0, 1, 1, 2, 2, 2, 3, 3, 3, 3};
    const int rj[10] = {0, 0, 1, 0, 1, 2, 0, 1, 2, 3};
    rbg = 4 * g + ri[r2];
    cb = 4 * g + rj[r2];
  }

  const _Float16* Ag = Q + (size_t)z * SD + (size_t)rbg * 128 * D_DIM;
  const _Float16* Bg = K + (size_t)z * SD + (size_t)cb * 128 * D_DIM;
  float4_t acc[4][4];
#pragma unroll
  for (int a = 0; a < 4; ++a)
#pragma unroll
    for (int b = 0; b < 4; ++b) acc[a][b] = (float4_t){0.f, 0.f, 0.f, 0.f};
  core128<false>(Ag, Bg, D_DIM, D_DIM, 12, lds, acc);

  const int tid = threadIdx.x;
  const int w = tid >> 6, l = tid & 63;
  const int wr = w >> 1, wc = w & 1;
  const int l15 = l & 15, l4 = l >> 4;
  _Float16* Pz = P + (size_t)z * S_DIM * S_DIM;
  float* rpz = rp + (size_t)z * S_DIM * 64;
#pragma unroll
  for (int mi = 0; mi < 4; ++mi) {
#pragma unroll
    for (int j = 0; j < 4; ++j) {
      int row = rbg * 128 + wr * 64 + mi * 16 + l4 * 4 + j;
      float rs = 0.f;
#pragma unroll
      for (int ni = 0; ni < 4; ++ni) {
        int col = cb * 128 + wc * 64 + ni * 16 + l15;
        float v = (col <= row) ? __expf(acc[mi][ni][j] * SCALE - 4.0f) : 0.f;
        _Float16 ph = (_Float16)v;
        Pz[(size_t)row * S_DIM + col] = ph;
        rs += (float)ph;
      }
#pragma unroll
      for (int d = 1; d < 16; d <<= 1) rs += __shfl_xor(rs, d);
      if (l15 == 0) rpz[(size_t)row * 64 + cb * 2 + wc] = rs;
    }
  }
}

// ---------------- gemm2: out = (P @ VT^T)/rsum — 768 balanced single-job blocks ---
// Placement-robust job permutation: h = bid%3, m = bid/3;
// pos = h==0 ? m : h==1 ? 511-m : 512+m; rank g = pos/24 (rbg = 31-g), q = pos%24.
// Under BOTH plausible CU-placement patterns (3 consecutive bids per CU, or
// bids {b, b+256, b+512}), each CU's 3 jobs mix heavy/mid/light with k-sums in
// [~43, ~53] vs ideal 49.5 -> makespan <= ~1.08x (was ~1.2-1.3x: gemm1 does the
// SAME 25,344 K-steps in 75 us vs gemm2's 88). xcd-slot mapping keeps each
// XCD's 3 VT panels (3 MB) L2-resident. rsum computed IN-KERNEL from rp.
__global__ __launch_bounds__(256) void gemm2_8_kernel(const _Float16* __restrict__ P,
                                                      const _Float16* __restrict__ VT,
                                                      float* __restrict__ outp,
                                                      const float* __restrict__ rp) {
  __shared__ __align__(16) char lds[32768];
  __shared__ float rsm[128];
  const int bid = blockIdx.x;
  const int h = bid % 3;
  const int m = bid / 3;
  const int pos = (h == 0) ? m : (h == 1) ? (511 - m) : (512 + m);
  const int g = pos / 24;           // rank: 0 = heaviest
  const int q = pos % 24;
  const int rbg = 31 - g;
  const int xcd = q & 7;
  const int slot = q >> 3;
  const int z = xcd >> 1;
  const int by = (xcd & 1) * 3 + slot;
  const int nt = 2 * (rbg + 1);

  const _Float16* Ag = P + (size_t)z * S_DIM * S_DIM + (size_t)rbg * 128 * S_DIM;
  const _Float16* Bg = VT + (size_t)z * SD + (size_t)by * 128 * S_DIM;
  float4_t acc[4][4];
#pragma unroll
  for (int a = 0; a < 4; ++a)
#pragma unroll
    for (int b = 0; b < 4; ++b) acc[a][b] = (float4_t){0.f, 0.f, 0.f, 0.f};
  core128<false>(Ag, Bg, S_DIM, S_DIM, nt, lds, acc);

  const int tid = threadIdx.x;
  // in-kernel rsum: row partials rp[(z*4096 + rbg*128 + t)*64 + i], i < nt
  if (tid < 128) {
    const float* p = rp + ((size_t)z * S_DIM + (size_t)rbg * 128 + tid) * 64;
    float s = 0.f;
    for (int i = 0; i < nt; ++i) s += p[i];
    rsm[tid] = 1.0f / s;
  }
  __syncthreads();

  const int w = tid >> 6, l = tid & 63;
  const int wr = w >> 1, wc = w & 1;
  const int l15 = l & 15, l4 = l >> 4;
#pragma unroll
  for (int mi = 0; mi < 4; ++mi) {
#pragma unroll
    for (int j = 0; j < 4; ++j) {
      int lrow = wr * 64 + mi * 16 + l4 * 4 + j;  // row within the 128-row block
      int row = rbg * 128 + lrow;                 // batch-local row
      float rinv = rsm[lrow];
#pragma unroll
      for (int ni = 0; ni < 4; ++ni) {
        int col = by * 128 + wc * 64 + ni * 16 + l15;
        outp[(size_t)z * SD + (size_t)row * D_DIM + col] = acc[mi][ni][j] * rinv;
      }
    }
  }
}

extern "C" void kernel_launch(void* const* d_in, const int* in_sizes, int n_in,
                              void* d_out, int out_size, void* d_ws, size_t ws_size,
                              hipStream_t stream) {
  const float* x = (const float*)d_in[0];
  const float* Wq = (const float*)d_in[1];
  const float* Wk = (const float*)d_in[2];
  const float* Wv = (const float*)d_in[3];
  float* out = (float*)d_out;
  char* ws = (char*)d_ws;

  const size_t XH_B = (size_t)M_DIM * D_DIM * 2;      // 25,165,824
  const size_t QKV_B = 3 * XH_B;                      // 75,497,472
  const size_t VT_B = XH_B;                           // 25,165,824
  const size_t WT_B = (size_t)3 * D_DIM * D_DIM * 2;  // 3,538,944
  const size_t BASE_END = XH_B + QKV_B + VT_B + WT_B; // 129,368,064

  _Float16* xh = (_Float16*)ws;
  _Float16* qkv = (_Float16*)(ws + XH_B);
  _Float16* Q = qkv;
  _Float16* K = qkv + (size_t)M_DIM * D_DIM;
  _Float16* vt = (_Float16*)(ws + XH_B + QKV_B);
  _Float16* wt = (_Float16*)(ws + XH_B + QKV_B + VT_B);

  // tier-A layout (rounds 4-19 prove ws_size >= 267,845,632)
  float* rp = (float*)(ws + BASE_END);                        // 4 MB
  _Float16* P = (_Float16*)(ws + BASE_END + (size_t)4259840); // 134 MB

  prep_kernel<<<dim3(12720), dim3(256), 0, stream>>>(x, Wq, Wk, Wv, xh, wt);
  proj8_kernel<<<dim3(2304), dim3(256), 0, stream>>>(xh, wt, qkv, vt);
  gemm1_8_kernel<<<dim3(2112), dim3(256), 0, stream>>>(Q, K, P, rp);
  gemm2_8_kernel<<<dim3(768), dim3(256), 0, stream>>>(P, vt, out, rp);
}